// Round 6
// baseline (99.634 us; speedup 1.0000x reference)
//
#include <hip/hip_runtime.h>

// Problem constants (fixed by setup_inputs)
#define B   8
#define C   256
#define H   128
#define W   128
#define HW  (H * W)
#define FH  512
#define FW  512

typedef float f32x2 __attribute__((ext_vector_type(2)));

// ---------------------------------------------------------------------------
// Kernel 1: strided 4x4 conv downsample of flows using runtime conv_w.
// ---------------------------------------------------------------------------
__global__ __launch_bounds__(256) void downsample_kernel(
    const float* __restrict__ flows,
    const float* __restrict__ conv_w,
    float* __restrict__ f)
{
    int idx = blockIdx.x * blockDim.x + threadIdx.x;
    if (idx >= B * 2 * H * W) return;
    int x = idx & (W - 1);
    int y = (idx >> 7) & (H - 1);
    int o = (idx >> 14) & 1;
    int b = idx >> 15;

    const float* fb = flows + (size_t)b * 2 * FH * FW;
    const float* cw = conv_w + o * 2 * 16;

    float acc = 0.f;
#pragma unroll
    for (int i = 0; i < 2; ++i) {
        const float* fi = fb + (size_t)i * FH * FW;
#pragma unroll
        for (int kh = 0; kh < 4; ++kh) {
            const float4 v = *reinterpret_cast<const float4*>(
                fi + (size_t)(4 * y + kh) * FW + 4 * x);
            const float* w = cw + i * 16 + kh * 4;
            acc += v.x * w[0] + v.y * w[1] + v.z * w[2] + v.w * w[3];
        }
    }
    f[idx] = acc;
}

// ---------------------------------------------------------------------------
// Kernel 2: bilinear warp, pair-load, ASM-forced 16-deep load batching.
// asm volatile global_load_dwordx2 cannot be sunk by the compiler; the
// s_waitcnt vmcnt(0) + sched_barrier(0) pair (rule #18) fences consumers.
// ---------------------------------------------------------------------------
#define PPB 64   // pixels per block
#define UN  8    // channel-steps per chunk -> 16 loads in flight

__global__ __launch_bounds__(256, 4) void warp_kernel(
    const float* __restrict__ feat,
    const float* __restrict__ f,
    float* __restrict__ out)
{
    __shared__ int   s_i0[PPB], s_i1[PPB];
    __shared__ float s_a0[PPB], s_b0[PPB], s_a1[PPB], s_b1[PPB];

    // XCD-aware swizzle (2048 blocks, 8 XCDs): each XCD owns one batch image.
    const int hw_bid = blockIdx.x;
    const int bid = (hw_bid & 7) * 256 + (hw_bid >> 3);

    const int tid = threadIdx.x;
    const int blocks_per_img = HW / PPB;               // 256
    const int b = bid / blocks_per_img;
    const int pix_base = (bid % blocks_per_img) * PPB;

    if (tid < PPB) {
        const int p = pix_base + tid;
        const int x = p & (W - 1);
        const int y = p >> 7;
        const float fx = f[(size_t)(b * 2 + 0) * HW + p];
        const float fy = f[(size_t)(b * 2 + 1) * HW + p];
        const float gx = (float)x + fx;
        const float gy = (float)y + fy;
        const float x0f = floorf(gx);
        const float y0f = floorf(gy);
        const float wx = gx - x0f;
        const float wy = gy - y0f;
        const int x0 = (int)x0f, y0 = (int)y0f;
        const int y1 = y0 + 1;

        const float u0 = 1.f - wx, u1 = wx;
        float A, Bv;
        if (x0 >= 0 && x0 <= W - 2)      { A = u0;  Bv = u1;  }
        else if (x0 == W - 1)            { A = 0.f; Bv = u0;  }
        else if (x0 == -1)               { A = u1;  Bv = 0.f; }
        else                             { A = 0.f; Bv = 0.f; }
        const int bx = min(max(x0, 0), W - 2);

        const float vy0 = (y0 >= 0 && y0 < H) ? 1.f : 0.f;
        const float vy1 = (y1 >= 0 && y1 < H) ? 1.f : 0.f;
        const int cy0 = min(max(y0, 0), H - 1);
        const int cy1 = min(max(y1, 0), H - 1);

        s_i0[tid] = cy0 * W + bx;
        s_i1[tid] = cy1 * W + bx;
        const float wy0 = (1.f - wy) * vy0;
        const float wy1 = wy * vy1;
        s_a0[tid] = A * wy0;  s_b0[tid] = Bv * wy0;
        s_a1[tid] = A * wy1;  s_b1[tid] = Bv * wy1;
    }
    __syncthreads();

    const int pl   = tid & (PPB - 1);   // pixel lane
    const int cofs = tid >> 6;          // wave id -> channel offset 0..3

    const int   i0 = s_i0[pl], i1 = s_i1[pl];
    const float a0 = s_a0[pl], b0 = s_b0[pl];
    const float a1 = s_a1[pl], b1 = s_b1[pl];

    const float* fb = feat + (size_t)b * C * HW;
    float*       ob = out  + (size_t)b * C * HW + pix_base;

    const float* pbase = fb + (size_t)cofs * HW;
    float*       q     = ob + (size_t)cofs * HW + pl;

    for (int k = 0; k < C / 4; k += UN) {
        f32x2 d0[UN], d1[UN];
#pragma unroll
        for (int u = 0; u < UN; ++u) {
            const float* pc = pbase + (size_t)(k + u) * 4 * HW;
            asm volatile("global_load_dwordx2 %0, %1, off"
                         : "=v"(d0[u]) : "v"(pc + i0));
            asm volatile("global_load_dwordx2 %0, %1, off"
                         : "=v"(d1[u]) : "v"(pc + i1));
        }
        asm volatile("s_waitcnt vmcnt(0)" ::: "memory");
        __builtin_amdgcn_sched_barrier(0);
#pragma unroll
        for (int u = 0; u < UN; ++u) {
            q[(size_t)(k + u) * 4 * HW] =
                d0[u].x * a0 + d0[u].y * b0 + d1[u].x * a1 + d1[u].y * b1;
        }
    }
}

// ---------------------------------------------------------------------------
extern "C" void kernel_launch(void* const* d_in, const int* in_sizes, int n_in,
                              void* d_out, int out_size, void* d_ws, size_t ws_size,
                              hipStream_t stream)
{
    const float* features = (const float*)d_in[0];
    const float* flows    = (const float*)d_in[1];
    const float* conv_w   = (const float*)d_in[2];
    float*       out      = (float*)d_out;
    float*       f        = (float*)d_ws;   // [B,2,H,W] = 1 MiB

    downsample_kernel<<<1024, 256, 0, stream>>>(flows, conv_w, f);
    warp_kernel<<<2048, 256, 0, stream>>>(features, f, out);
}